// Round 1
// baseline (106.983 us; speedup 1.0000x reference)
//
#include <hip/hip_runtime.h>
#include <math.h>

#define NCC   32            // tessellation cells
#define NROW  31            // NC-1 constraints
#define NCOL  64            // 2*NC params
#define LDL   65            // padded LDS row stride (doubles)
#define EPSF  1e-10f

// ---------------------------------------------------------------------------
// Setup kernel: reproduce numpy's SVD null-space basis action A = B @ theta.
// numpy -> dgesdd (m=31 < n=64, jobz='A', n >= MNTHR=56) -> Path 4t:
//   Vt[31:, :] == Q[31:, :] from the Householder LQ factorization (dgelqf).
// Hence A_flat = B @ theta = Q^T [0_31; theta] = H(1) H(2) ... H(31) u.
// Done in double precision, matching dlarfg's sign convention.
// ---------------------------------------------------------------------------
__global__ __launch_bounds__(64) void setup_A(const float* __restrict__ theta,
                                              float* __restrict__ Aout) {
    __shared__ double Lm[NROW][LDL];
    __shared__ double tauS[NROW];
    __shared__ double uS[NCOL];
    const int tid = threadIdx.x;  // 64 threads, one wave

    // build L (constraint matrix), zero-padded
    for (int idx = tid; idx < NROW * LDL; idx += 64) ((double*)Lm)[idx] = 0.0;
    __syncthreads();
    if (tid < NROW) {
        const int k = tid + 1;
        const double xk = (double)k / (double)NCC;
        Lm[tid][2 * tid]     = xk;
        Lm[tid][2 * tid + 1] = 1.0;
        Lm[tid][2 * tid + 2] = -xk;
        Lm[tid][2 * tid + 3] = -1.0;
    }
    __syncthreads();

    // Householder LQ (dgelq2 semantics). Reflector i support: cols [i, 2i+3].
    for (int i = 0; i < NROW; ++i) {
        int E = 2 * i + 3; if (E > NCOL - 1) E = NCOL - 1;

        // all lanes redundantly compute xnorm^2 (broadcast LDS reads)
        double xn2 = 0.0;
        for (int p = i + 1; p <= E; ++p) { double w = Lm[i][p]; xn2 += w * w; }
        const double alpha = Lm[i][i];
        double tau = 0.0, scale = 0.0;
        if (xn2 != 0.0) {
            const double nrm  = sqrt(alpha * alpha + xn2);
            const double beta = (alpha >= 0.0) ? -nrm : nrm;   // dlarfg sign
            tau   = (beta - alpha) / beta;
            scale = 1.0 / (alpha - beta);
        }
        __syncthreads();
        // store scaled v in row i; implicit v_i = 1 stored explicitly
        if (tid >= i + 1 && tid <= E) Lm[i][tid] *= scale;
        if (tid == i) { Lm[i][i] = 1.0; tauS[i] = tau; }
        __syncthreads();
        // apply H(i) to rows j > i (row-parallel)
        if (tid > i && tid < NROW) {
            const int j = tid;
            double s = 0.0;
            for (int p = i; p <= E; ++p) s += Lm[i][p] * Lm[j][p];
            s *= tau;
            for (int p = i; p <= E; ++p) Lm[j][p] -= s * Lm[i][p];
        }
        __syncthreads();
    }

    // u = [0_31; theta]; apply H(i), i = 30..0  =>  u <- Q^T u
    if (tid < NCOL) uS[tid] = (tid >= NROW) ? (double)theta[tid - NROW] : 0.0;
    __syncthreads();
    for (int i = NROW - 1; i >= 0; --i) {
        int E = 2 * i + 3; if (E > NCOL - 1) E = NCOL - 1;
        double contrib = (tid >= i && tid <= E) ? Lm[i][tid] * uS[tid] : 0.0;
        for (int off = 32; off > 0; off >>= 1)
            contrib += __shfl_xor(contrib, off, 64);
        const double s = contrib * tauS[i];
        __syncthreads();
        if (tid >= i && tid <= E) uS[tid] -= s * Lm[i][tid];
        __syncthreads();
    }
    if (tid < NCOL) Aout[tid] = (float)uS[tid];  // Aout[2c]=a_c, Aout[2c+1]=b_c
}

// ---------------------------------------------------------------------------
// Main kernel: closed-form CPAB integration, f32, mirroring reference exactly.
// ---------------------------------------------------------------------------
__global__ __launch_bounds__(256) void cpab_flow(const float* __restrict__ x_in,
                                                 const float* __restrict__ Atab,
                                                 float* __restrict__ out,
                                                 int n) {
    __shared__ float As[2 * NCC];
    if (threadIdx.x < 2 * NCC) As[threadIdx.x] = Atab[threadIdx.x];
    __syncthreads();

    const int gi = blockIdx.x * blockDim.x + threadIdx.x;
    if (gi >= n) return;

    const float h   = 1.0f / (float)NCC;
    const float INF = __builtin_inff();

    float xs = x_in[gi];
    int   c  = (int)floorf(xs * (float)NCC);
    c = min(max(c, 0), NCC - 1);
    float t  = 1.0f;
    float lj = 0.0f;

#pragma unroll 1
    for (int it = 0; it < NCC; ++it) {
        if (!__any(t > 0.0f)) break;
        if (t > 0.0f) {
            const float a = As[2 * c];
            const float b = As[2 * c + 1];
            const float v = a * xs + b;

            const float left  = (c == 0)       ? -INF : (float)c * h;
            const float right = (c == NCC - 1) ?  INF : (float)(c + 1) * h;
            const float xc    = (v > 0.0f) ? right : left;
            const bool  finite = (fabsf(xc) != INF);
            const float xcs   = finite ? xc : xs;

            const bool  big  = fabsf(a) > EPSF;
            const float a_s  = big ? a : 1.0f;
            const float vc   = a * xcs + b;
            const float r    = vc / ((v == 0.0f) ? 1.0f : v);
            const float th_a = logf(fmaxf(r, EPSF)) / a_s;
            const float th_b = (xcs - xs) / ((fabsf(b) > EPSF) ? b : 1.0f);
            float t_hit = big ? ((r > EPSF) ? th_a : INF) : th_b;
            const bool valid = finite && (v != 0.0f) && (t_hit > 0.0f);
            t_hit = valid ? t_hit : INF;

            const bool  cross = (t_hit < t);
            const float dt    = cross ? t_hit : t;       // t_hit finite if cross
            const float boa   = b / a_s;
            const float psi   = big ? (expf(a * dt) * (xs + boa) - boa)
                                    : (xs + b * dt);
            xs = cross ? xcs : psi;
            lj += a * dt;
            t   = cross ? (t - dt) : 0.0f;
            if (cross) c = min(max(c + ((v > 0.0f) ? 1 : -1), 0), NCC - 1);
        }
    }

    out[gi]     = xs;   // z
    out[n + gi] = lj;   // log|dz/dx|
}

extern "C" void kernel_launch(void* const* d_in, const int* in_sizes, int n_in,
                              void* d_out, int out_size, void* d_ws, size_t ws_size,
                              hipStream_t stream) {
    const float* x     = (const float*)d_in[0];
    const float* theta = (const float*)d_in[1];
    float*       out   = (float*)d_out;
    float*       Atab  = (float*)d_ws;   // 64 floats: per-cell (a, b)
    const int    n     = in_sizes[0];

    setup_A<<<1, 64, 0, stream>>>(theta, Atab);
    const int blocks = (n + 255) / 256;
    cpab_flow<<<blocks, 256, 0, stream>>>(x, Atab, out, n);
}

// Round 4
// 49.359 us; speedup vs baseline: 2.1675x; 2.1675x over previous
//
#include <hip/hip_runtime.h>
#include <math.h>

#define NCC  32
#define EPSF 1e-10f
#define PPT  4

// ---------------------------------------------------------------------------
// Compile-time reproduction of numpy's SVD null-space basis (validated R1):
// np.linalg.svd -> dgesdd (m=31 < n=64, jobz='A', n >= MNTHR) -> Path 4t:
// Vt[31:, :] == Q[31:, :] from the Householder LQ (dgelqf) of L.
// A = B @ theta = Q^T [0_31; theta]  =>  A_p = sum_j M[j][p] * theta_j with
// M[:,j] = H(1)...H(31) e_{31+j}. Done in double at COMPILE TIME; entries
// cast to f32 — matching the reference's jnp.asarray(B_NP, float32) cast.
// ---------------------------------------------------------------------------
struct MTab { float mt[33][64]; };

constexpr double csqrt_(double x) {
    double y = x > 1.0 ? x : 1.0;
    for (int i = 0; i < 80; ++i) y = 0.5 * (y + x / y);
    return y;
}

constexpr MTab make_mtab() {
    double Lm[31][64] = {};
    for (int k = 1; k < 32; ++k) {
        double xk = (double)k / 32.0;
        Lm[k - 1][2 * (k - 1)]     = xk;
        Lm[k - 1][2 * (k - 1) + 1] = 1.0;
        Lm[k - 1][2 * k]           = -xk;
        Lm[k - 1][2 * k + 1]       = -1.0;
    }
    double tau[31] = {};
    for (int i = 0; i < 31; ++i) {
        int E = 2 * i + 3; if (E > 63) E = 63;
        double xn2 = 0.0;
        for (int p = i + 1; p <= E; ++p) xn2 += Lm[i][p] * Lm[i][p];
        const double alpha = Lm[i][i];
        double tu = 0.0, sc = 0.0;
        if (xn2 != 0.0) {
            const double nrm  = csqrt_(alpha * alpha + xn2);
            const double beta = (alpha >= 0.0) ? -nrm : nrm;   // dlarfg sign
            tu = (beta - alpha) / beta;
            sc = 1.0 / (alpha - beta);
        }
        for (int p = i + 1; p <= E; ++p) Lm[i][p] *= sc;
        Lm[i][i] = 1.0;
        tau[i] = tu;
        for (int j = i + 1; j < 31; ++j) {
            double s = 0.0;
            for (int p = i; p <= E; ++p) s += Lm[i][p] * Lm[j][p];
            s *= tu;
            for (int p = i; p <= E; ++p) Lm[j][p] -= s * Lm[i][p];
        }
    }
    MTab o{};
    for (int col = 0; col < 33; ++col) {
        double u[64] = {};
        u[31 + col] = 1.0;
        for (int i = 30; i >= 0; --i) {   // u <- H(1)...H(31) u (R1-validated)
            int E = 2 * i + 3; if (E > 63) E = 63;
            double s = 0.0;
            for (int p = i; p <= E; ++p) s += Lm[i][p] * u[p];
            s *= tau[i];
            for (int p = i; p <= E; ++p) u[p] -= s * Lm[i][p];
        }
        for (int p = 0; p < 64; ++p) o.mt[col][p] = (float)u[p];
    }
    return o;
}

__constant__ const MTab dM = make_mtab();

// ---------------------------------------------------------------------------
// One closed-form flow step — R1's reference-exact arithmetic (IEEE divides,
// libm logf/expf, unfused mul/add). Table entries are bit-identical
// precomputes only: boa = b/a_s (deterministic IEEE divide), vL/vR (same
// unfused expression as the per-step a*xcs+b). ib is selected only when
// |a| <= 1e-10 (never for gaussian A) so its rounding cannot matter.
// ---------------------------------------------------------------------------
struct PState { float xs, t, lj; int c; };

__device__ __forceinline__ bool flow_step(PState& s, const float (*tab)[NCC]) {
    const float INF = __builtin_inff();
    const int   c   = s.c;
    const float a   = tab[0][c];
    const float b   = tab[1][c];
    const float boa = tab[2][c];          // b / a_s  (IEEE divide, = per-step)
    const float ib  = tab[3][c];          // 1 / (|b|>EPS ? b : 1)  (dead path)

    const float v      = __fadd_rn(__fmul_rn(a, s.xs), b);
    const bool  dir    = v > 0.0f;
    const bool  finite = dir ? (c < NCC - 1) : (c > 0);
    const float xb     = __fmul_rn((float)(c + (dir ? 1 : 0)), 0.03125f);
    const float xcs    = finite ? xb : s.xs;
    const float vc     = finite ? (dir ? tab[5][c] : tab[4][c]) : v;

    const bool  v0   = (v == 0.0f);
    const float r    = vc / (v0 ? 1.0f : v);          // IEEE divide
    const bool  big  = fabsf(a) > EPSF;
    const float a_s  = big ? a : 1.0f;
    const float th_a = logf(fmaxf(r, EPSF)) / a_s;    // libm log, IEEE divide
    const float th_b = __fmul_rn(__fsub_rn(xcs, s.xs), ib);
    float t_hit = big ? ((r > EPSF) ? th_a : INF) : th_b;
    const bool valid = finite && !v0 && (t_hit > 0.0f);
    t_hit = valid ? t_hit : INF;

    const bool  cross = t_hit < s.t;
    const float dt    = cross ? t_hit : s.t;
    const float ad    = __fmul_rn(a, dt);
    const float ea    = expf(ad);                     // libm exp
    const float psi   = big ? __fsub_rn(__fmul_rn(ea, __fadd_rn(s.xs, boa)), boa)
                            : __fadd_rn(s.xs, __fmul_rn(b, dt));
    s.xs = cross ? xcs : psi;
    s.lj = __fadd_rn(s.lj, ad);
    s.t  = cross ? __fsub_rn(s.t, dt) : 0.0f;
    const int cn = c + (cross ? (dir ? 1 : -1) : 0);
    s.c = min(max(cn, 0), NCC - 1);
    return s.t == 0.0f;
}

__device__ __forceinline__ int cell_of(float x) {
    const int c = (int)floorf(__fmul_rn(x, 32.0f));
    return min(max(c, 0), NCC - 1);
}

// ---------------------------------------------------------------------------
// Main kernel: per-block table preamble + per-lane 4-point state machine.
// ---------------------------------------------------------------------------
__global__ __launch_bounds__(256) void cpab_flow(const float* __restrict__ x_in,
                                                 const float* __restrict__ theta,
                                                 float* __restrict__ out, int n) {
    __shared__ float sA[2 * NCC];
    __shared__ float tab[6][NCC];   // a, b, b/a_s, 1/b', vL, vR

    const int tid = threadIdx.x;
    if (tid < 64) {
        float acc = 0.0f;
#pragma unroll
        for (int j = 0; j < 33; ++j) acc = fmaf(dM.mt[j][tid], theta[j], acc);
        sA[tid] = acc;
    }
    __syncthreads();
    if (tid < NCC) {
        const float a   = sA[2 * tid];
        const float b   = sA[2 * tid + 1];
        const bool  big = fabsf(a) > EPSF;
        const float a_s = big ? a : 1.0f;
        const float xL  = __fmul_rn((float)tid, 0.03125f);
        const float xR  = __fmul_rn((float)(tid + 1), 0.03125f);
        tab[0][tid] = a;
        tab[1][tid] = b;
        tab[2][tid] = b / a_s;                            // IEEE divide
        tab[3][tid] = 1.0f / ((fabsf(b) > EPSF) ? b : 1.0f);
        tab[4][tid] = __fadd_rn(__fmul_rn(a, xL), b);
        tab[5][tid] = __fadd_rn(__fmul_rn(a, xR), b);
    }
    __syncthreads();

    const int nq       = n >> 2;
    const int gi       = blockIdx.x * blockDim.x + tid;
    const int nthreads = gridDim.x * blockDim.x;

    if (gi < nq) {
        const int    base = gi << 2;
        const float4 xv   = *reinterpret_cast<const float4*>(x_in + base);
        float i0 = xv.y, i1 = xv.z, i2 = xv.w;
        PState s; s.xs = xv.x; s.t = 1.0f; s.lj = 0.0f; s.c = cell_of(xv.x);
        int k  = 0;
        int it = 0;
        float* pz = out + base;
        float* pj = out + n + base;
        while (__any(s.t > 0.0f)) {
            if (s.t > 0.0f) {
                const bool fin = flow_step(s, tab);
                ++it;
                if (fin || it == NCC) {           // scan length = 32, like ref
                    pz[k] = s.xs;
                    pj[k] = s.lj;
                    ++k;
                    s.xs = i0; i0 = i1; i1 = i2;  // pop next input
                    s.c  = cell_of(s.xs);
                    s.lj = 0.0f;
                    it   = 0;
                    s.t  = (k < PPT) ? 1.0f : 0.0f;
                }
            }
        }
    }

    // tail (n % 4 != 0) — unused at n = 2^21 but kept for generality
    for (int idx = (nq << 2) + gi; idx < n; idx += nthreads) {
        PState s; s.xs = x_in[idx]; s.t = 1.0f; s.lj = 0.0f; s.c = cell_of(s.xs);
        for (int it = 0; it < NCC && s.t > 0.0f; ++it) flow_step(s, tab);
        out[idx]     = s.xs;
        out[n + idx] = s.lj;
    }
}

extern "C" void kernel_launch(void* const* d_in, const int* in_sizes, int n_in,
                              void* d_out, int out_size, void* d_ws, size_t ws_size,
                              hipStream_t stream) {
    (void)d_ws; (void)ws_size; (void)n_in; (void)out_size;
    const float* x     = (const float*)d_in[0];
    const float* theta = (const float*)d_in[1];
    float*       out   = (float*)d_out;
    const int    n     = in_sizes[0];

    const int nq     = n >> 2;
    int       blocks = (nq + 255) / 256;
    if (blocks < 1) blocks = 1;
    cpab_flow<<<blocks, 256, 0, stream>>>(x, theta, out, n);
}

// Round 5
// 23.604 us; speedup vs baseline: 4.5325x; 2.0911x over previous
//
#include <hip/hip_runtime.h>
#include <math.h>

#define NCC  32
#define EPSF 1e-10f

// ---------------------------------------------------------------------------
// Compile-time reproduction of numpy's SVD null-space basis (validated R1/R4):
// np.linalg.svd -> dgesdd (m=31 < n=64, jobz='A', n >= MNTHR) -> Path 4t:
// Vt[31:, :] == Q[31:, :] from the Householder LQ (dgelqf) of L.
// A = B @ theta = Q^T [0_31; theta]. Double precision at compile time; cast
// to f32 per entry (matches reference's jnp.asarray(B_NP, float32)).
// ---------------------------------------------------------------------------
struct MTab { float mt[33][64]; };

constexpr double csqrt_(double x) {
    double y = x > 1.0 ? x : 1.0;
    for (int i = 0; i < 80; ++i) y = 0.5 * (y + x / y);
    return y;
}

constexpr MTab make_mtab() {
    double Lm[31][64] = {};
    for (int k = 1; k < 32; ++k) {
        double xk = (double)k / 32.0;
        Lm[k - 1][2 * (k - 1)]     = xk;
        Lm[k - 1][2 * (k - 1) + 1] = 1.0;
        Lm[k - 1][2 * k]           = -xk;
        Lm[k - 1][2 * k + 1]       = -1.0;
    }
    double tau[31] = {};
    for (int i = 0; i < 31; ++i) {
        int E = 2 * i + 3; if (E > 63) E = 63;
        double xn2 = 0.0;
        for (int p = i + 1; p <= E; ++p) xn2 += Lm[i][p] * Lm[i][p];
        const double alpha = Lm[i][i];
        double tu = 0.0, sc = 0.0;
        if (xn2 != 0.0) {
            const double nrm  = csqrt_(alpha * alpha + xn2);
            const double beta = (alpha >= 0.0) ? -nrm : nrm;   // dlarfg sign
            tu = (beta - alpha) / beta;
            sc = 1.0 / (alpha - beta);
        }
        for (int p = i + 1; p <= E; ++p) Lm[i][p] *= sc;
        Lm[i][i] = 1.0;
        tau[i] = tu;
        for (int j = i + 1; j < 31; ++j) {
            double s = 0.0;
            for (int p = i; p <= E; ++p) s += Lm[i][p] * Lm[j][p];
            s *= tu;
            for (int p = i; p <= E; ++p) Lm[j][p] -= s * Lm[i][p];
        }
    }
    MTab o{};
    for (int col = 0; col < 33; ++col) {
        double u[64] = {};
        u[31 + col] = 1.0;
        for (int i = 30; i >= 0; --i) {
            int E = 2 * i + 3; if (E > 63) E = 63;
            double s = 0.0;
            for (int p = i; p <= E; ++p) s += Lm[i][p] * u[p];
            s *= tau[i];
            for (int p = i; p <= E; ++p) u[p] -= s * Lm[i][p];
        }
        for (int p = 0; p < 64; ++p) o.mt[col][p] = (float)u[p];
    }
    return o;
}

__constant__ const MTab dM = make_mtab();

// ---------------------------------------------------------------------------
// Key invariant (bit-level): after any crossing, xs is the exact boundary
// float (c±1)*2^-5 and the direction sign(v) never changes along a trajectory
// (v(t) = v0*e^{at}; float sign-flip-at-entry cases yield r==1.0 -> t_hit==0
// -> invalid -> terminal, so no backward cross is ever taken). Hence t_hit,
// a*t_hit for steps >= 1 are per-(cell,dir) constants, precomputed below with
// the reference's EXACT expressions (same input bits -> same libm/IEEE bits).
// ---------------------------------------------------------------------------
__global__ __launch_bounds__(256) void cpab_flow(const float* __restrict__ x_in,
                                                 const float* __restrict__ theta,
                                                 float* __restrict__ out, int n) {
    __shared__ float  sA[64];
    __shared__ float  aS[NCC], bS[NCC], boaS[NCC], vLS[NCC], vRS[NCC];
    __shared__ float2 TA[2][NCC];   // [1]=right-moving, [0]=left-moving: {t_hit, a*t_hit}

    const int tid = threadIdx.x;
    const float INF = __builtin_inff();

    if (tid < 64) {
        float acc = 0.0f;
#pragma unroll
        for (int j = 0; j < 33; ++j) acc = fmaf(dM.mt[j][tid], theta[j], acc);
        sA[tid] = acc;
    }
    __syncthreads();
    if (tid < NCC) {
        const float a   = sA[2 * tid];
        const float b   = sA[2 * tid + 1];
        const bool  big = fabsf(a) > EPSF;
        aS[tid]   = a;
        bS[tid]   = b;
        boaS[tid] = b / (big ? a : 1.0f);                       // IEEE divide
        vLS[tid]  = __fadd_rn(__fmul_rn(a, __fmul_rn((float)tid,       0.03125f)), b);
        vRS[tid]  = __fadd_rn(__fmul_rn(a, __fmul_rn((float)(tid + 1), 0.03125f)), b);
    }
    __syncthreads();
    if (tid < 2 * NCC) {
        // build TA[d][c]: reference step with xs = entry boundary of cell c
        // for arrival direction d (1 = moving right, entry = c*h; 0 = left,
        // entry = (c+1)*h). All expressions/bits identical to the reference.
        const int   c     = tid & 31;
        const int   d     = tid >> 5;
        const float a     = aS[c];
        const float b     = bS[c];
        const float entry = __fmul_rn((float)(c + (d ? 0 : 1)), 0.03125f);
        const float v     = d ? vLS[c] : vRS[c];   // a*entry+b, same bits
        const bool  dirA  = v > 0.0f;
        const bool  fin   = dirA ? (c < NCC - 1) : (c > 0);
        const float xb    = __fmul_rn((float)(c + (dirA ? 1 : 0)), 0.03125f);
        const float xcs   = fin ? xb : entry;
        const float vc    = fin ? (dirA ? vRS[c] : vLS[c]) : v;
        const bool  v0    = (v == 0.0f);
        const float r     = vc / (v0 ? 1.0f : v);               // IEEE divide
        const bool  big   = fabsf(a) > EPSF;
        const float a_s   = big ? a : 1.0f;
        const float th_a  = logf(fmaxf(r, EPSF)) / a_s;         // libm + divide
        const float bb    = (fabsf(b) > EPSF) ? b : 1.0f;
        const float th_b  = __fsub_rn(xcs, entry) / bb;
        float t_hit = big ? ((r > EPSF) ? th_a : INF) : th_b;
        const bool valid = fin && !v0 && (t_hit > 0.0f);
        t_hit = valid ? t_hit : INF;
        TA[d][c] = make_float2(t_hit, __fmul_rn(a, t_hit));     // lj increment
    }
    __syncthreads();

    const int gi = blockIdx.x * blockDim.x + tid;
    if (gi >= n) return;

    const float x0 = x_in[gi];
    int c = (int)floorf(__fmul_rn(x0, 32.0f));
    c = min(max(c, 0), NCC - 1);

    // ---- step 0: full reference math from arbitrary x0 (wave-uniform) ----
    float a = aS[c], b = bS[c];
    const float v    = __fadd_rn(__fmul_rn(a, x0), b);
    const bool  dirA = v > 0.0f;
    const bool  fin  = dirA ? (c < NCC - 1) : (c > 0);
    const float xb   = __fmul_rn((float)(c + (dirA ? 1 : 0)), 0.03125f);
    const float xcs  = fin ? xb : x0;
    const float vc   = fin ? (dirA ? vRS[c] : vLS[c]) : v;
    const bool  v0   = (v == 0.0f);
    const float r    = vc / (v0 ? 1.0f : v);                    // IEEE divide
    bool  big  = fabsf(a) > EPSF;
    float a_s  = big ? a : 1.0f;
    const float th_a = logf(fmaxf(r, EPSF)) / a_s;              // libm + divide
    const float bb   = (fabsf(b) > EPSF) ? b : 1.0f;
    const float th_b = __fsub_rn(xcs, x0) / bb;
    float th = big ? ((r > EPSF) ? th_a : INF) : th_b;
    const bool valid = fin && !v0 && (th > 0.0f);
    th = valid ? th : INF;

    float t = 1.0f, lj = 0.0f;
    const bool cross0 = th < t;
    const int  d      = dirA ? 1 : -1;
    bool done = !cross0;
    if (cross0) {
        t  = __fsub_rn(t, th);
        lj = __fmul_rn(a, th);   // == fadd(0, fmul(a,th)) up to sign-of-zero
        c += d;
    }

    // ---- crossing loop: ~7 VALU/iter, per-(cell,dir) constants from LDS ----
    const float2* TAd = TA[dirA ? 1 : 0];
    while (__any(!done)) {
        if (!done) {
            const float2 ta = TAd[c];
            if (ta.x < t) {
                t  = __fsub_rn(t, ta.x);
                lj = __fadd_rn(lj, ta.y);
                c += d;
            } else {
                done = true;
            }
        }
    }

    // ---- terminal step (wave-uniform): dt = t, psi closed form ----
    const float xs = cross0 ? __fmul_rn((float)(c + (dirA ? 0 : 1)), 0.03125f) : x0;
    a = aS[c]; b = bS[c];
    big = fabsf(a) > EPSF;
    const float boa = boaS[c];
    const float ad  = __fmul_rn(a, t);
    const float ea  = expf(ad);                                  // libm exp
    const float psi = big ? __fsub_rn(__fmul_rn(ea, __fadd_rn(xs, boa)), boa)
                          : __fadd_rn(xs, __fmul_rn(b, t));
    lj = __fadd_rn(lj, ad);

    out[gi]     = psi;
    out[n + gi] = lj;
}

extern "C" void kernel_launch(void* const* d_in, const int* in_sizes, int n_in,
                              void* d_out, int out_size, void* d_ws, size_t ws_size,
                              hipStream_t stream) {
    (void)d_ws; (void)ws_size; (void)n_in; (void)out_size;
    const float* x     = (const float*)d_in[0];
    const float* theta = (const float*)d_in[1];
    float*       out   = (float*)d_out;
    const int    n     = in_sizes[0];

    const int blocks = (n + 255) / 256;
    cpab_flow<<<blocks, 256, 0, stream>>>(x, theta, out, n);
}

// Round 6
// 19.269 us; speedup vs baseline: 5.5520x; 1.2250x over previous
//
#include <hip/hip_runtime.h>
#include <math.h>

#define NCC  32
#define EPSF 1e-10f
#define NBLK 2048

// ---------------------------------------------------------------------------
// Compile-time reproduction of numpy's SVD null-space basis (validated R1/R4):
// np.linalg.svd -> dgesdd (m=31 < n=64, jobz='A', n >= MNTHR) -> Path 4t:
// Vt[31:, :] == Q[31:, :] from the Householder LQ (dgelqf) of L.
// A = B @ theta = Q^T [0_31; theta]. Double precision at compile time; cast
// to f32 per entry (matches reference's jnp.asarray(B_NP, float32)).
// ---------------------------------------------------------------------------
struct MTab { float mt[33][64]; };

constexpr double csqrt_(double x) {
    double y = x > 1.0 ? x : 1.0;
    for (int i = 0; i < 80; ++i) y = 0.5 * (y + x / y);
    return y;
}

constexpr MTab make_mtab() {
    double Lm[31][64] = {};
    for (int k = 1; k < 32; ++k) {
        double xk = (double)k / 32.0;
        Lm[k - 1][2 * (k - 1)]     = xk;
        Lm[k - 1][2 * (k - 1) + 1] = 1.0;
        Lm[k - 1][2 * k]           = -xk;
        Lm[k - 1][2 * k + 1]       = -1.0;
    }
    double tau[31] = {};
    for (int i = 0; i < 31; ++i) {
        int E = 2 * i + 3; if (E > 63) E = 63;
        double xn2 = 0.0;
        for (int p = i + 1; p <= E; ++p) xn2 += Lm[i][p] * Lm[i][p];
        const double alpha = Lm[i][i];
        double tu = 0.0, sc = 0.0;
        if (xn2 != 0.0) {
            const double nrm  = csqrt_(alpha * alpha + xn2);
            const double beta = (alpha >= 0.0) ? -nrm : nrm;   // dlarfg sign
            tu = (beta - alpha) / beta;
            sc = 1.0 / (alpha - beta);
        }
        for (int p = i + 1; p <= E; ++p) Lm[i][p] *= sc;
        Lm[i][i] = 1.0;
        tau[i] = tu;
        for (int j = i + 1; j < 31; ++j) {
            double s = 0.0;
            for (int p = i; p <= E; ++p) s += Lm[i][p] * Lm[j][p];
            s *= tu;
            for (int p = i; p <= E; ++p) Lm[j][p] -= s * Lm[i][p];
        }
    }
    MTab o{};
    for (int col = 0; col < 33; ++col) {
        double u[64] = {};
        u[31 + col] = 1.0;
        for (int i = 30; i >= 0; --i) {
            int E = 2 * i + 3; if (E > 63) E = 63;
            double s = 0.0;
            for (int p = i; p <= E; ++p) s += Lm[i][p] * u[p];
            s *= tau[i];
            for (int p = i; p <= E; ++p) u[p] -= s * Lm[i][p];
        }
        for (int p = 0; p < 64; ++p) o.mt[col][p] = (float)u[p];
    }
    return o;
}

__constant__ const MTab dM = make_mtab();

__device__ __forceinline__ int cidx(int v) { return min(max(v, 0), NCC - 1); }

// ---------------------------------------------------------------------------
// Invariants (validated R5, bit-level): after a crossing, xs is the exact
// boundary float (c')*2^-5; direction never flips; hence t_hit and a*t_hit
// for steps >= 1 are per-(cell,dir) constants. The crossing loop's ADDRESS
// sequence (c, c+d, c+2d, ...) is known after step 0 — only the trip count is
// data-dependent — so LDS reads are prefetched in double-buffered quads and
// never sit on the critical path. All value-producing arithmetic is identical
// to R5 (reference-exact: IEEE divides, libm logf/expf, unfused mul/add).
// ---------------------------------------------------------------------------
__global__ __launch_bounds__(256) void cpab_flow(const float* __restrict__ x_in,
                                                 const float* __restrict__ theta,
                                                 float* __restrict__ out, int n) {
    __shared__ float  sA[64];
    __shared__ float  aS[NCC], bS[NCC], boaS[NCC], vLS[NCC], vRS[NCC];
    __shared__ float2 TA[2][NCC];   // [1]=right-moving, [0]=left: {t_hit, a*t_hit}

    const int   tid = threadIdx.x;
    const float INF = __builtin_inff();

    if (tid < 64) {
        float acc = 0.0f;
#pragma unroll
        for (int j = 0; j < 33; ++j) acc = fmaf(dM.mt[j][tid], theta[j], acc);
        sA[tid] = acc;
    }
    __syncthreads();
    if (tid < NCC) {
        const float a   = sA[2 * tid];
        const float b   = sA[2 * tid + 1];
        const bool  big = fabsf(a) > EPSF;
        aS[tid]   = a;
        bS[tid]   = b;
        boaS[tid] = b / (big ? a : 1.0f);                       // IEEE divide
        vLS[tid]  = __fadd_rn(__fmul_rn(a, __fmul_rn((float)tid,       0.03125f)), b);
        vRS[tid]  = __fadd_rn(__fmul_rn(a, __fmul_rn((float)(tid + 1), 0.03125f)), b);
    }
    __syncthreads();
    if (tid < 2 * NCC) {
        // TA[d][c]: reference step with xs = entry boundary of cell c for
        // arrival direction d (1: entry = c*h; 0: entry = (c+1)*h).
        const int   c     = tid & 31;
        const int   d     = tid >> 5;
        const float a     = aS[c];
        const float b     = bS[c];
        const float entry = __fmul_rn((float)(c + (d ? 0 : 1)), 0.03125f);
        const float v     = d ? vLS[c] : vRS[c];
        const bool  dirA  = v > 0.0f;
        const bool  fin   = dirA ? (c < NCC - 1) : (c > 0);
        const float xb    = __fmul_rn((float)(c + (dirA ? 1 : 0)), 0.03125f);
        const float xcs   = fin ? xb : entry;
        const float vc    = fin ? (dirA ? vRS[c] : vLS[c]) : v;
        const bool  v0    = (v == 0.0f);
        const float r     = vc / (v0 ? 1.0f : v);               // IEEE divide
        const bool  big   = fabsf(a) > EPSF;
        const float a_s   = big ? a : 1.0f;
        const float th_a  = logf(fmaxf(r, EPSF)) / a_s;         // libm + divide
        const float bb    = (fabsf(b) > EPSF) ? b : 1.0f;
        const float th_b  = __fsub_rn(xcs, entry) / bb;
        float t_hit = big ? ((r > EPSF) ? th_a : INF) : th_b;
        const bool valid = fin && !v0 && (t_hit > 0.0f);
        t_hit = valid ? t_hit : INF;
        TA[d][c] = make_float2(t_hit, __fmul_rn(a, t_hit));
    }
    __syncthreads();

    const int stride = gridDim.x * blockDim.x;
    for (int gi = blockIdx.x * blockDim.x + tid; gi < n; gi += stride) {
        const float x0 = x_in[gi];
        int c = (int)floorf(__fmul_rn(x0, 32.0f));
        c = min(max(c, 0), NCC - 1);

        // ---- step 0: full reference math from arbitrary x0 ----
        float a = aS[c], b = bS[c];
        const float v    = __fadd_rn(__fmul_rn(a, x0), b);
        const bool  dirA = v > 0.0f;
        const bool  fin  = dirA ? (c < NCC - 1) : (c > 0);
        const float xb   = __fmul_rn((float)(c + (dirA ? 1 : 0)), 0.03125f);
        const float xcs  = fin ? xb : x0;
        const float vc   = fin ? (dirA ? vRS[c] : vLS[c]) : v;
        const bool  v0   = (v == 0.0f);
        const float r    = vc / (v0 ? 1.0f : v);                // IEEE divide
        bool  big  = fabsf(a) > EPSF;
        float a_s  = big ? a : 1.0f;
        const float th_a = logf(fmaxf(r, EPSF)) / a_s;          // libm + divide
        const float bb   = (fabsf(b) > EPSF) ? b : 1.0f;
        const float th_b = __fsub_rn(xcs, x0) / bb;
        float th = big ? ((r > EPSF) ? th_a : INF) : th_b;
        const bool valid = fin && !v0 && (th > 0.0f);
        th = valid ? th : INF;

        float t = 1.0f, lj = 0.0f;
        const bool cross0 = th < t;
        const int  d      = dirA ? 1 : -1;
        bool done = !cross0;
        if (cross0) {
            t  = __fsub_rn(t, th);
            lj = __fmul_rn(a, th);
            c += d;
        }

        // ---- crossing loop: double-buffered quad prefetch, issue-bound ----
        const float2* TAd = TA[dirA ? 1 : 0];
        int pc = c;
        float2 buf[4];
#pragma unroll
        for (int k = 0; k < 4; ++k) buf[k] = TAd[cidx(pc + k * d)];
        while (__any(!done)) {
            float2 nbuf[4];
            const int nc = pc + 4 * d;
#pragma unroll
            for (int k = 0; k < 4; ++k) nbuf[k] = TAd[cidx(nc + k * d)];
#pragma unroll
            for (int k = 0; k < 4; ++k) {
                if (!done) {
                    if (buf[k].x < t) {
                        t  = __fsub_rn(t, buf[k].x);
                        lj = __fadd_rn(lj, buf[k].y);
                        c += d;
                    } else {
                        done = true;
                    }
                }
            }
#pragma unroll
            for (int k = 0; k < 4; ++k) buf[k] = nbuf[k];
            pc = nc;
        }

        // ---- terminal step: dt = t, psi closed form (reference-exact) ----
        const float xs = cross0 ? __fmul_rn((float)(c + (dirA ? 0 : 1)), 0.03125f)
                                : x0;
        a = aS[c]; b = bS[c];
        big = fabsf(a) > EPSF;
        const float boa = boaS[c];
        const float ad  = __fmul_rn(a, t);
        const float ea  = expf(ad);                              // libm exp
        const float psi = big ? __fsub_rn(__fmul_rn(ea, __fadd_rn(xs, boa)), boa)
                              : __fadd_rn(xs, __fmul_rn(b, t));
        out[gi]     = psi;
        out[n + gi] = __fadd_rn(lj, ad);
    }
}

extern "C" void kernel_launch(void* const* d_in, const int* in_sizes, int n_in,
                              void* d_out, int out_size, void* d_ws, size_t ws_size,
                              hipStream_t stream) {
    (void)d_ws; (void)ws_size; (void)n_in; (void)out_size;
    const float* x     = (const float*)d_in[0];
    const float* theta = (const float*)d_in[1];
    float*       out   = (float*)d_out;
    const int    n     = in_sizes[0];

    int blocks = (n + 255) / 256;
    if (blocks > NBLK) blocks = NBLK;
    cpab_flow<<<blocks, 256, 0, stream>>>(x, theta, out, n);
}

// Round 7
// 19.009 us; speedup vs baseline: 5.6280x; 1.0137x over previous
//
#include <hip/hip_runtime.h>
#include <math.h>

#define NCC  32
#define EPSF 1e-10f

// ---------------------------------------------------------------------------
// Compile-time reproduction of numpy's SVD null-space basis (validated R1/R4):
// np.linalg.svd -> dgesdd (m=31 < n=64, jobz='A', n >= MNTHR) -> Path 4t:
// Vt[31:, :] == Q[31:, :] from the Householder LQ (dgelqf) of L.
// A = B @ theta = Q^T [0_31; theta]. Double precision at compile time; cast
// to f32 per entry (matches reference's jnp.asarray(B_NP, float32)).
// ---------------------------------------------------------------------------
struct MTab { float mt[33][64]; };

constexpr double csqrt_(double x) {
    double y = x > 1.0 ? x : 1.0;
    for (int i = 0; i < 80; ++i) y = 0.5 * (y + x / y);
    return y;
}

constexpr MTab make_mtab() {
    double Lm[31][64] = {};
    for (int k = 1; k < 32; ++k) {
        double xk = (double)k / 32.0;
        Lm[k - 1][2 * (k - 1)]     = xk;
        Lm[k - 1][2 * (k - 1) + 1] = 1.0;
        Lm[k - 1][2 * k]           = -xk;
        Lm[k - 1][2 * k + 1]       = -1.0;
    }
    double tau[31] = {};
    for (int i = 0; i < 31; ++i) {
        int E = 2 * i + 3; if (E > 63) E = 63;
        double xn2 = 0.0;
        for (int p = i + 1; p <= E; ++p) xn2 += Lm[i][p] * Lm[i][p];
        const double alpha = Lm[i][i];
        double tu = 0.0, sc = 0.0;
        if (xn2 != 0.0) {
            const double nrm  = csqrt_(alpha * alpha + xn2);
            const double beta = (alpha >= 0.0) ? -nrm : nrm;   // dlarfg sign
            tu = (beta - alpha) / beta;
            sc = 1.0 / (alpha - beta);
        }
        for (int p = i + 1; p <= E; ++p) Lm[i][p] *= sc;
        Lm[i][i] = 1.0;
        tau[i] = tu;
        for (int j = i + 1; j < 31; ++j) {
            double s = 0.0;
            for (int p = i; p <= E; ++p) s += Lm[i][p] * Lm[j][p];
            s *= tu;
            for (int p = i; p <= E; ++p) Lm[j][p] -= s * Lm[i][p];
        }
    }
    MTab o{};
    for (int col = 0; col < 33; ++col) {
        double u[64] = {};
        u[31 + col] = 1.0;
        for (int i = 30; i >= 0; --i) {
            int E = 2 * i + 3; if (E > 63) E = 63;
            double s = 0.0;
            for (int p = i; p <= E; ++p) s += Lm[i][p] * u[p];
            s *= tau[i];
            for (int p = i; p <= E; ++p) u[p] -= s * Lm[i][p];
        }
        for (int p = 0; p < 64; ++p) o.mt[col][p] = (float)u[p];
    }
    return o;
}

__constant__ const MTab dM = make_mtab();

// ---------------------------------------------------------------------------
// Invariants (validated R5/R6, bit-level): after a crossing, xs is the exact
// boundary float c'*2^-5; direction never flips; t_hit and a*t_hit for
// steps >= 1 are per-(cell,dir) constants. Crossing loop walks the exact
// fsub/fadd chain two links per iteration; guard entries {INF,0} pad the
// table so no index clamping is needed (guards only reach lanes whose
// compare fails, so their values never enter live state).
// ---------------------------------------------------------------------------
__global__ __launch_bounds__(256) void cpab_flow(const float* __restrict__ x_in,
                                                 const float* __restrict__ theta,
                                                 float* __restrict__ out, int n) {
    __shared__ float  sA[64];
    __shared__ float  aS[NCC], bS[NCC], boaS[NCC], vLS[NCC], vRS[NCC];
    __shared__ float2 TAP[2][NCC + 8];   // +4 guard on each side

    const int   tid = threadIdx.x;
    const float INF = __builtin_inff();

    if (tid < 64) {
        float acc = 0.0f;
#pragma unroll
        for (int j = 0; j < 33; ++j) acc = fmaf(dM.mt[j][tid], theta[j], acc);
        sA[tid] = acc;
    }
    __syncthreads();
    if (tid < NCC) {
        const float a   = sA[2 * tid];
        const float b   = sA[2 * tid + 1];
        const bool  big = fabsf(a) > EPSF;
        aS[tid]   = a;
        bS[tid]   = b;
        boaS[tid] = b / (big ? a : 1.0f);                       // IEEE divide
        vLS[tid]  = __fadd_rn(__fmul_rn(a, __fmul_rn((float)tid,       0.03125f)), b);
        vRS[tid]  = __fadd_rn(__fmul_rn(a, __fmul_rn((float)(tid + 1), 0.03125f)), b);
    }
    __syncthreads();
    if (tid < 2 * (NCC + 8)) {
        // TAP[d][j]: j in [4,36) -> reference step for cell c=j-4, arrival
        // direction d (1: entry = c*h; 0: entry = (c+1)*h); else {INF,0}.
        const int   dd = tid / (NCC + 8);
        const int   j  = tid % (NCC + 8);
        float2 val = make_float2(INF, 0.0f);
        if (j >= 4 && j < NCC + 4) {
            const int   c     = j - 4;
            const float a     = aS[c];
            const float b     = bS[c];
            const float entry = __fmul_rn((float)(c + (dd ? 0 : 1)), 0.03125f);
            const float v     = dd ? vLS[c] : vRS[c];
            const bool  dirA  = v > 0.0f;
            const bool  fin   = dirA ? (c < NCC - 1) : (c > 0);
            const float xb    = __fmul_rn((float)(c + (dirA ? 1 : 0)), 0.03125f);
            const float xcs   = fin ? xb : entry;
            const float vc    = fin ? (dirA ? vRS[c] : vLS[c]) : v;
            const bool  v0    = (v == 0.0f);
            const float r     = vc / (v0 ? 1.0f : v);           // IEEE divide
            const bool  big   = fabsf(a) > EPSF;
            const float a_s   = big ? a : 1.0f;
            const float th_a  = logf(fmaxf(r, EPSF)) / a_s;     // libm + divide
            const float bb    = (fabsf(b) > EPSF) ? b : 1.0f;
            const float th_b  = __fsub_rn(xcs, entry) / bb;
            float t_hit = big ? ((r > EPSF) ? th_a : INF) : th_b;
            const bool valid = fin && !v0 && (t_hit > 0.0f);
            t_hit = valid ? t_hit : INF;
            val = make_float2(t_hit, __fmul_rn(a, t_hit));
        }
        TAP[dd][j] = val;
    }
    __syncthreads();

    const int base = (blockIdx.x * blockDim.x + tid) << 2;
    if (base >= n) return;

    const float4 xv = *reinterpret_cast<const float4*>(x_in + base);
    float4 zo, jo;

#pragma unroll
    for (int q = 0; q < 4; ++q) {
        const float x0 = (q == 0) ? xv.x : (q == 1) ? xv.y : (q == 2) ? xv.z : xv.w;
        int c = (int)floorf(__fmul_rn(x0, 32.0f));
        c = min(max(c, 0), NCC - 1);

        // ---- step 0: full reference math from arbitrary x0 ----
        float a = aS[c], b = bS[c];
        const float v    = __fadd_rn(__fmul_rn(a, x0), b);
        const bool  dirA = v > 0.0f;
        const bool  fin  = dirA ? (c < NCC - 1) : (c > 0);
        const float xb   = __fmul_rn((float)(c + (dirA ? 1 : 0)), 0.03125f);
        const float xcs  = fin ? xb : x0;
        const float vc   = fin ? (dirA ? vRS[c] : vLS[c]) : v;
        const bool  v0   = (v == 0.0f);
        const float r    = vc / (v0 ? 1.0f : v);                // IEEE divide
        const bool  big  = fabsf(a) > EPSF;
        const float a_s  = big ? a : 1.0f;
        const float th_a = logf(fmaxf(r, EPSF)) / a_s;          // libm + divide
        float th_b = 0.0f;
        if (__any(!big)) {   // dead for gaussian A; exact when taken
            const float bb = (fabsf(b) > EPSF) ? b : 1.0f;
            th_b = __fsub_rn(xcs, x0) / bb;
        }
        float th = big ? ((r > EPSF) ? th_a : INF) : th_b;
        const bool valid = fin && !v0 && (th > 0.0f);
        th = valid ? th : INF;

        float t = 1.0f, lj = 0.0f;
        const bool cross0 = th < t;
        const int  d      = dirA ? 1 : -1;
        if (cross0) {
            t  = __fsub_rn(t, th);
            lj = __fmul_rn(a, th);
            c += d;
        }

        // ---- crossing loop: 2 exact chain links per iteration ----
        const float2* TAd = TAP[dirA ? 1 : 0] + 4;   // TAd[c] valid, c in [-4,35]
        bool active = cross0;
        while (__any(active)) {
            if (active) {
                const float2 A1 = TAd[c];
                const float2 A2 = TAd[c + d];
                const bool  x1  = A1.x < t;
                const float t1  = __fsub_rn(t, A1.x);
                const float l1  = __fadd_rn(lj, A1.y);
                const bool  x2  = x1 && (A2.x < t1);
                t  = x2 ? __fsub_rn(t1, A2.x) : (x1 ? t1 : t);
                lj = x2 ? __fadd_rn(l1, A2.y) : (x1 ? l1 : lj);
                c += x2 ? 2 * d : (x1 ? d : 0);
                active = x2;
            }
        }

        // ---- terminal step: dt = t, psi closed form (reference-exact) ----
        const float xs = cross0 ? __fmul_rn((float)(c + (dirA ? 0 : 1)), 0.03125f)
                                : x0;
        a = aS[c]; b = bS[c];
        const bool  bigf = fabsf(a) > EPSF;
        const float boa  = boaS[c];
        const float ad   = __fmul_rn(a, t);
        const float ea   = expf(ad);                             // libm exp
        const float psi  = bigf ? __fsub_rn(__fmul_rn(ea, __fadd_rn(xs, boa)), boa)
                                : __fadd_rn(xs, __fmul_rn(b, t));
        const float ljo  = __fadd_rn(lj, ad);
        if (q == 0) { zo.x = psi; jo.x = ljo; }
        if (q == 1) { zo.y = psi; jo.y = ljo; }
        if (q == 2) { zo.z = psi; jo.z = ljo; }
        if (q == 3) { zo.w = psi; jo.w = ljo; }
    }

    *reinterpret_cast<float4*>(out + base)     = zo;
    *reinterpret_cast<float4*>(out + n + base) = jo;
}

extern "C" void kernel_launch(void* const* d_in, const int* in_sizes, int n_in,
                              void* d_out, int out_size, void* d_ws, size_t ws_size,
                              hipStream_t stream) {
    (void)d_ws; (void)ws_size; (void)n_in; (void)out_size;
    const float* x     = (const float*)d_in[0];
    const float* theta = (const float*)d_in[1];
    float*       out   = (float*)d_out;
    const int    n     = in_sizes[0];

    const int threads = (n + 3) / 4;
    const int blocks  = (threads + 255) / 256;
    cpab_flow<<<blocks, 256, 0, stream>>>(x, theta, out, n);
}